// Round 4
// baseline (325.049 us; speedup 1.0000x reference)
//
#include <hip/hip_runtime.h>
#include <hip/hip_bf16.h>
#include <math.h>

typedef short bf16x8 __attribute__((ext_vector_type(8)));
typedef float f32x4 __attribute__((ext_vector_type(4)));
typedef short short4v __attribute__((ext_vector_type(4)));
typedef short short8v __attribute__((ext_vector_type(8)));

__device__ __forceinline__ short f2bf(float f) {
  unsigned u = __builtin_bit_cast(unsigned, f);
  unsigned r = (u + 0x7FFFu + ((u >> 16) & 1u)) >> 16;
  return (short)r;
}
__device__ __forceinline__ float bf2f(short s) {
  unsigned u = ((unsigned)(unsigned short)s) << 16;
  return __builtin_bit_cast(float, u);
}

typedef __attribute__((address_space(1))) const unsigned g_u32;
typedef __attribute__((address_space(3))) unsigned l_u32;
__device__ __forceinline__ void gload_lds16(const short* g, short* l) {
  __builtin_amdgcn_global_load_lds((g_u32*)g, (l_u32*)l, 16, 0, 0);
}

// ---------------- casts ----------------

__global__ __launch_bounds__(256) void k_cast_x(const float* __restrict__ x, short* __restrict__ xb) {
  int tid = blockIdx.x * 256 + threadIdx.x;
  int d4 = tid & 255;
  int sb = tid >> 8;
  int s = sb & 2047;
  int b = sb >> 11;
  float4 v = *((const float4*)(x + (((size_t)s * 8 + b) << 10)) + d4);
  short4v o;
  o.x = f2bf(v.x); o.y = f2bf(v.y); o.z = f2bf(v.z); o.w = f2bf(v.w);
  *((short4v*)(xb + (((size_t)b * 2048 + s) << 10)) + d4) = o;
}

__global__ __launch_bounds__(256) void k_cast_w(const float* __restrict__ Wq, const float* __restrict__ Wk,
                                                const float* __restrict__ Wv, short* __restrict__ Wcat) {
  int tid = blockIdx.x * 256 + threadIdx.x;
  int d4 = tid & 255;
  int n = tid >> 8;
  const float* src = (n < 1024) ? Wq : (n < 2048 ? Wk : Wv);
  int nl = n & 1023;
  float4 v = *((const float4*)(src + ((size_t)nl << 10)) + d4);
  short4v o;
  o.x = f2bf(v.x); o.y = f2bf(v.y); o.z = f2bf(v.z); o.w = f2bf(v.w);
  *((short4v*)(Wcat + ((size_t)n << 10)) + d4) = o;
}

__global__ __launch_bounds__(256) void k_cast_bias(const float* __restrict__ bq, const float* __restrict__ bk,
                                                   const float* __restrict__ bv, float* __restrict__ biascat) {
  int i = blockIdx.x * 256 + threadIdx.x;
  if (i < 3072) biascat[i] = (i < 1024) ? bq[i] : (i < 2048 ? bk[i & 1023] : bv[i & 1023]);
}

// ---------------- 256x256-tile GEMM core, free-drift waves ----------------
// C[256][256] = A[256, K-contig, LDA] * B^T[256, K-contig, LDB]
// 512 threads = 8 waves (2M x 4N); per-wave 128x64 -> acc[8][4].
// LDS per operand: [2buf][2 K-halves of 32][256 rows][32] bf16; A+B = 128 KiB.
// Slot swizzle: slot' = slot ^ ((row>>1)&3) (involution; inverse-swizzled global
// source, linear LDS dest). Conflict-free on ds_read_b128 (verified: 0 in R2/R3).
// Per K-tile: exactly 2 barriers + 1 counted vmcnt, NO intra-tile barriers:
//   barrier A  (all waves' fragment reads of tile t-1 complete: their MFMAs
//              consumed them before this point in program order)
//   stage(t+1) -> other buffer (8 global_load_lds)
//   vmcnt(8)   (drain stage(t), keep stage(t+1) in flight)
//   barrier B  (all waves drained stage(t) -> buf fully written)
//   compute: kk0 {12 ds_read_b128; 32 MFMA}; kk1 {12 reads; 32 MFMA}
// Compiler inserts fine-grained lgkmcnt; waves drift within the tile so the
// LDS port and the matrix pipe overlap across waves.
template <int LDA, int LDB>
__device__ __forceinline__ void gemm256_core(const short* __restrict__ Ag, const short* __restrict__ Bg,
                                             int NT, short* __restrict__ lds, f32x4 (&acc)[8][4], int tid) {
  const int lane = tid & 63;
  const int wid = tid >> 6;
  const int wm = wid >> 2, wn = wid & 3;
  const int r15 = lane & 15;
  const int g = lane >> 4;
  const int co = ((g ^ ((r15 >> 1) & 3)) << 3);   // swizzled element offset within 32-elem row
  short* As = lds;
  short* Bs = lds + 32768;

  auto stage_tile = [&](int bufv, int kElem) {
#pragma unroll
    for (int kkv = 0; kkv < 2; ++kkv) {
      short* Al = As + (bufv * 2 + kkv) * 8192;
      short* Bl = Bs + (bufv * 2 + kkv) * 8192;
      int ke = kElem + kkv * 32;
#pragma unroll
      for (int i = 0; i < 2; ++i) {
        int c = i * 512 + tid;
        int r = c >> 2, s = c & 3;
        int gk = ke + ((s ^ ((r >> 1) & 3)) << 3);
        gload_lds16(Ag + (size_t)r * LDA + gk, Al + c * 8);
      }
#pragma unroll
      for (int i = 0; i < 2; ++i) {
        int c = i * 512 + tid;
        int r = c >> 2, s = c & 3;
        int gk = ke + ((s ^ ((r >> 1) & 3)) << 3);
        gload_lds16(Bg + (size_t)r * LDB + gk, Bl + c * 8);
      }
    }
  };

  stage_tile(0, 0);   // prologue: K-tile 0 -> buf 0

  for (int t = 0; t < NT; ++t) {
    const int buf = t & 1;
    __builtin_amdgcn_s_barrier();                       // A
    if (t + 1 < NT) {
      stage_tile(buf ^ 1, (t + 1) << 6);
      asm volatile("s_waitcnt vmcnt(8)" ::: "memory");  // drain stage(t)
    } else {
      asm volatile("s_waitcnt vmcnt(0)" ::: "memory");
    }
    __builtin_amdgcn_s_barrier();                       // B: buf fully staged

    const short* A0 = As + ((buf * 2 + 0) * 256 + wm * 128 + r15) * 32 + co;
    const short* B0 = Bs + ((buf * 2 + 0) * 256 + wn * 64 + r15) * 32 + co;
    const short* A1 = As + ((buf * 2 + 1) * 256 + wm * 128 + r15) * 32 + co;
    const short* B1 = Bs + ((buf * 2 + 1) * 256 + wn * 64 + r15) * 32 + co;

    {
      bf16x8 af[8], bfr[4];
#pragma unroll
      for (int mi = 0; mi < 8; ++mi) af[mi] = *(const bf16x8*)(A0 + mi * 512);
#pragma unroll
      for (int ni = 0; ni < 4; ++ni) bfr[ni] = *(const bf16x8*)(B0 + ni * 512);
      __builtin_amdgcn_s_setprio(1);
#pragma unroll
      for (int mi = 0; mi < 8; ++mi)
#pragma unroll
        for (int ni = 0; ni < 4; ++ni)
          acc[mi][ni] = __builtin_amdgcn_mfma_f32_16x16x32_bf16(af[mi], bfr[ni], acc[mi][ni], 0, 0, 0);
      __builtin_amdgcn_s_setprio(0);
    }
    {
      bf16x8 af[8], bfr[4];
#pragma unroll
      for (int mi = 0; mi < 8; ++mi) af[mi] = *(const bf16x8*)(A1 + mi * 512);
#pragma unroll
      for (int ni = 0; ni < 4; ++ni) bfr[ni] = *(const bf16x8*)(B1 + ni * 512);
      __builtin_amdgcn_s_setprio(1);
#pragma unroll
      for (int mi = 0; mi < 8; ++mi)
#pragma unroll
        for (int ni = 0; ni < 4; ++ni)
          acc[mi][ni] = __builtin_amdgcn_mfma_f32_16x16x32_bf16(af[mi], bfr[ni], acc[mi][ni], 0, 0, 0);
      __builtin_amdgcn_s_setprio(0);
    }
  }
}

// ---------------- QKV projection: (16384,3072) = Xb (16384,1024) * Wcat^T + bias ----------------
// Q, K stored (B,S,A) bf16; V stored TRANSPOSED as Vt (B,A,S) bf16.
__global__ __launch_bounds__(512, 1) void k_proj(const short* __restrict__ Xb, const short* __restrict__ Wc,
                                                 const float* __restrict__ biascat,
                                                 short* __restrict__ Q, short* __restrict__ K, short* __restrict__ Vt) {
  __shared__ __align__(16) short lds[65536];
  int tid = threadIdx.x;
  int wg = blockIdx.x;                       // 768 blocks
  int swz = (wg & 7) * 96 + (wg >> 3);       // XCD swizzle (768 % 8 == 0, bijective)
  int mt = swz / 12, nt = swz % 12;
  int m0 = mt << 8, n0 = nt << 8;
  f32x4 acc[8][4] = {};
  gemm256_core<1024, 1024>(Xb + (size_t)m0 * 1024, Wc + (size_t)n0 * 1024, 16, lds, acc, tid);
  int lane = tid & 63, wid = tid >> 6;
  int wm = wid >> 2, wn = wid & 3;
  int r15 = lane & 15;
  int which = n0 >> 10;
  int nbase = n0 & 1023;
  if (which == 2) {
#pragma unroll
    for (int ni = 0; ni < 4; ++ni) {
      int cth = wn * 64 + ni * 16 + r15;
      int a = nbase + cth;
      float bv = biascat[n0 + cth];
#pragma unroll
      for (int mi = 0; mi < 8; ++mi) {
        int r = m0 + wm * 128 + mi * 16 + ((lane >> 4) << 2);
        int b = r >> 11, s = r & 2047;
        short4v o;
#pragma unroll
        for (int j = 0; j < 4; ++j) o[j] = f2bf(acc[mi][ni][j] + bv);
        *(short4v*)(Vt + ((size_t)b << 21) + ((size_t)a << 11) + s) = o;
      }
    }
  } else {
    short* outb = (which == 0) ? Q : K;
#pragma unroll
    for (int ni = 0; ni < 4; ++ni) {
      int cth = wn * 64 + ni * 16 + r15;
      float bv = biascat[n0 + cth];
#pragma unroll
      for (int mi = 0; mi < 8; ++mi)
#pragma unroll
        for (int j = 0; j < 4; ++j) {
          int r = m0 + wm * 128 + mi * 16 + ((lane >> 4) << 2) + j;
          outb[((size_t)r << 10) + nbase + cth] = f2bf(acc[mi][ni][j] + bv);
        }
    }
  }
}

// ---------------- QK^T: causal lower-tri 256-tiles, scaled, bf16 scores ----------------
__global__ __launch_bounds__(512, 1) void k_qk(const short* __restrict__ Q, const short* __restrict__ K,
                                               short* __restrict__ Sc) {
  int nt = blockIdx.x, mt = blockIdx.y, b = blockIdx.z;
  if (nt > mt) return;
  __shared__ __align__(16) short lds[65536];
  int tid = threadIdx.x;
  int m0 = mt << 8, n0 = nt << 8;
  const short* Qb = Q + ((size_t)b << 21);
  const short* Kb = K + ((size_t)b << 21);
  f32x4 acc[8][4] = {};
  gemm256_core<1024, 1024>(Qb + (size_t)m0 * 1024, Kb + (size_t)n0 * 1024, 16, lds, acc, tid);
  short* Sb = Sc + ((size_t)b << 22);
  int lane = tid & 63, wid = tid >> 6;
  int wm = wid >> 2, wn = wid & 3;
  int r15 = lane & 15;
#pragma unroll
  for (int mi = 0; mi < 8; ++mi)
#pragma unroll
    for (int ni = 0; ni < 4; ++ni)
#pragma unroll
      for (int j = 0; j < 4; ++j) {
        int r = m0 + wm * 128 + mi * 16 + ((lane >> 4) << 2) + j;
        int c = n0 + wn * 64 + ni * 16 + r15;
        Sb[((size_t)r << 11) + c] = f2bf(acc[mi][ni][j] * 0.03125f);
      }
}

// ---------------- row softmax in-place, causal; zero-fill to 256-tile edge ----------------
__global__ __launch_bounds__(256) void k_softmax(short* __restrict__ Sc) {
  int row = blockIdx.x;
  int b = row >> 11, q = row & 2047;
  short* Pr = Sc + ((size_t)b << 22) + ((size_t)q << 11);
  int T = ((q >> 8) + 1) << 8;          // padded causal length (multiple of 256)
  int tid = threadIdx.x, lane = tid & 63, wid = tid >> 6;
  int k0 = tid << 3;
  float v[8];
  if (k0 < T) {
    short8v raw = *(const short8v*)(Pr + k0);
#pragma unroll
    for (int j = 0; j < 8; ++j) v[j] = (k0 + j <= q) ? bf2f(raw[j]) : -__builtin_inff();
  } else {
#pragma unroll
    for (int j = 0; j < 8; ++j) v[j] = -__builtin_inff();
  }
  float mx = v[0];
#pragma unroll
  for (int j = 1; j < 8; ++j) mx = fmaxf(mx, v[j]);
  for (int off = 1; off < 64; off <<= 1) mx = fmaxf(mx, __shfl_xor(mx, off, 64));
  __shared__ float red[2][4];
  if (lane == 0) red[0][wid] = mx;
  __syncthreads();
  mx = fmaxf(fmaxf(red[0][0], red[0][1]), fmaxf(red[0][2], red[0][3]));
  float e[8], sum = 0.f;
#pragma unroll
  for (int j = 0; j < 8; ++j) {
    e[j] = exp2f((v[j] - mx) * 1.4426950408889634f);
    sum += e[j];
  }
  for (int off = 1; off < 64; off <<= 1) sum += __shfl_xor(sum, off, 64);
  if (lane == 0) red[1][wid] = sum;
  __syncthreads();
  sum = red[1][0] + red[1][1] + red[1][2] + red[1][3];
  float inv = 1.f / sum;
  if (k0 < T) {
    short8v o;
#pragma unroll
    for (int j = 0; j < 8; ++j) o[j] = (k0 + j <= q) ? f2bf(e[j] * inv) : (short)0;
    *(short8v*)(Pr + k0) = o;
  }
}

// ---------------- PV: out (S,B,A) f32 = P (B,S,S) * Vt (B,A,S)^T ----------------
__global__ __launch_bounds__(512, 1) void k_pv(const short* __restrict__ P, const short* __restrict__ Vt,
                                               float* __restrict__ out) {
  int nt = blockIdx.x, mt = blockIdx.y, b = blockIdx.z;
  __shared__ __align__(16) short lds[65536];
  int tid = threadIdx.x;
  int m0 = mt << 8, n0 = nt << 8;
  const short* Pb = P + ((size_t)b << 22);
  const short* Vtb = Vt + ((size_t)b << 21);
  f32x4 acc[8][4] = {};
  gemm256_core<2048, 2048>(Pb + (size_t)m0 * 2048, Vtb + (size_t)n0 * 2048, 4 * (mt + 1), lds, acc, tid);
  int lane = tid & 63, wid = tid >> 6;
  int wm = wid >> 2, wn = wid & 3;
  int r15 = lane & 15;
#pragma unroll
  for (int mi = 0; mi < 8; ++mi)
#pragma unroll
    for (int ni = 0; ni < 4; ++ni)
#pragma unroll
      for (int j = 0; j < 4; ++j) {
        int r = m0 + wm * 128 + mi * 16 + ((lane >> 4) << 2) + j;  // q
        int c = n0 + wn * 64 + ni * 16 + r15;                      // a
        out[((size_t)r << 13) + ((size_t)b << 10) + c] = acc[mi][ni][j];
      }
}

extern "C" void kernel_launch(void* const* d_in, const int* in_sizes, int n_in,
                              void* d_out, int out_size, void* d_ws, size_t ws_size,
                              hipStream_t stream) {
  const float* x  = (const float*)d_in[0];
  const float* Wq = (const float*)d_in[1];
  const float* bq = (const float*)d_in[2];
  const float* Wk = (const float*)d_in[3];
  const float* bk = (const float*)d_in[4];
  const float* Wv = (const float*)d_in[5];
  const float* bv = (const float*)d_in[6];
  float* out = (float*)d_out;
  char* ws = (char*)d_ws;

  short* xb   = (short*)(ws);                    // 33,554,432 B
  short* Wcat = (short*)(ws + 33554432);         //  6,291,456 B
  float* bias = (float*)(ws + 39845888);         //     12,288 B
  short* Q    = (short*)(ws + 39858176);         // 33,554,432 B
  short* K    = (short*)(ws + 73412608);         // 33,554,432 B
  short* Vt   = (short*)(ws + 106967040);        // 33,554,432 B (written transposed by k_proj)
  short* Sc   = (short*)(ws + 140521472);        // 67,108,864 B

  k_cast_x<<<16384, 256, 0, stream>>>(x, xb);
  k_cast_w<<<3072, 256, 0, stream>>>(Wq, Wk, Wv, Wcat);
  k_cast_bias<<<12, 256, 0, stream>>>(bq, bk, bv, bias);
  k_proj<<<768, 512, 0, stream>>>(xb, Wcat, bias, Q, K, Vt);
  k_qk<<<dim3(8, 8, 8), 512, 0, stream>>>(Q, K, Sc);
  k_softmax<<<16384, 256, 0, stream>>>(Sc);
  k_pv<<<dim3(4, 8, 8), 512, 0, stream>>>(Sc, Vt, out);
}